// Round 7
// baseline (1048.748 us; speedup 1.0000x reference)
//
#include <hip/hip_runtime.h>
#include <float.h>

typedef __attribute__((ext_vector_type(8))) short short8;
typedef __attribute__((ext_vector_type(4))) float f32x4;
typedef unsigned short u16;
typedef unsigned int u32;

#define N_ROWS 65536
#define K_CB   4096
#define D_DIM  256
#define TAU    2.0e-3f    // >= 2*(3-term split err ~2e-4 + np-vs-exact ~1e-4) with margin
#define CAP    8
#define RR     8

// ws offsets (bytes)
#define WS_COUNTER 0
#define WS_ESQ     256
#define WS_IDX     (WS_ESQ + K_CB*4)
#define WS_FLAG    (WS_IDX + N_ROWS*4)
#define WS_PART    (WS_FLAG + N_ROWS*4)
#define NUM_OUT_BLOCKS 16384

// d_out scratch offsets (bytes) — inside quantized region, overwritten by output_kernel
#define SC_EHP  256
#define SC_ELP  (SC_EHP + K_CB*D_DIM*2)      // +2 MB
#define SC_CAND (SC_ELP + K_CB*D_DIM*2)      // +2 MB
#define SC_CNT  (SC_CAND + N_ROWS*CAP*4)     // +2 MB

// ---------- helpers ----------
__device__ __forceinline__ u16 f2bf(float x) {
  unsigned int u = __float_as_uint(x);
  unsigned int r = (u + 0x7fffu + ((u >> 16) & 1u)) >> 16;
  return (u16)r;
}
__device__ __forceinline__ float bf2f(u16 b) {
  return __uint_as_float((unsigned int)b << 16);
}
// np-exact final combine: fl( fl(zsq+esq) - fl(2*dot) )
__device__ __forceinline__ float np_score(float zsq, float ek, float dot) {
#pragma clang fp contract(off)
  float t1 = zsq + ek;
  float t2 = 2.0f * dot;
  return t1 - t2;
}

// ---------- numpy-emulated pairwise sum of squares ----------
__device__ __forceinline__ float np_sum128_sq(const float* p) {
#pragma clang fp contract(off)
  float r0 = p[0]*p[0], r1 = p[1]*p[1], r2 = p[2]*p[2], r3 = p[3]*p[3];
  float r4 = p[4]*p[4], r5 = p[5]*p[5], r6 = p[6]*p[6], r7 = p[7]*p[7];
  for (int i = 8; i < 128; i += 8) {
    r0 += p[i+0]*p[i+0]; r1 += p[i+1]*p[i+1];
    r2 += p[i+2]*p[i+2]; r3 += p[i+3]*p[i+3];
    r4 += p[i+4]*p[i+4]; r5 += p[i+5]*p[i+5];
    r6 += p[i+6]*p[i+6]; r7 += p[i+7]*p[i+7];
  }
  return ((r0+r1)+(r2+r3))+((r4+r5)+(r6+r7));
}
__device__ __forceinline__ float np_sumsq256(const float* p) {
#pragma clang fp contract(off)
  float a = np_sum128_sq(p);
  float b = np_sum128_sq(p + 128);
  return a + b;
}

__global__ __launch_bounds__(256) void esq_np_kernel(const float* __restrict__ cb,
                                                     float* __restrict__ esq) {
  const int k = blockIdx.x * 256 + threadIdx.x;
  esq[k] = np_sumsq256(cb + (size_t)k * D_DIM);
}

// ---------- codebook split hi/lo, MFMA-A-fragment-permuted ----------
// Per 32-code chunk c, elem off = c*8192 + sub*4096 + step*512 + lq*128 + code16*8 + j
// A-frag read (lane l): code16 = l&15, lq = l>>4 -> contiguous 1024B per wave read.
__global__ __launch_bounds__(256) void esplit3_kernel(const float* __restrict__ cb,
                                                      u16* __restrict__ ehp,
                                                      u16* __restrict__ elp) {
  const int g  = blockIdx.x * 256 + threadIdx.x;   // k*32 + d8
  const int k  = g >> 5, d8 = g & 31;
  const int c  = k >> 5, sub = (k >> 4) & 1, code16 = k & 15;
  const int step = d8 >> 2, lq = d8 & 3;
  const float* src = cb + (size_t)k * D_DIM + d8 * 8;
  float4 f0 = *(const float4*)src;
  float4 f1 = *(const float4*)(src + 4);
  float f[8] = {f0.x,f0.y,f0.z,f0.w,f1.x,f1.y,f1.z,f1.w};
  short8 h, lo;
  #pragma unroll
  for (int j = 0; j < 8; ++j) {
    u16 hb = f2bf(f[j]);
    h[j]  = (short)hb;
    lo[j] = (short)f2bf(f[j] - bf2f(hb));
  }
  const size_t off = (size_t)c*8192 + sub*4096 + step*512 + lq*128 + code16*8;
  *(short8*)(ehp + off) = h;
  *(short8*)(elp + off) = lo;
}

// ---------- fused 3-term split-bf16 MFMA + shortlist collect ----------
// 256 thr = 4 waves; wave owns 32 rows exclusively (zh/zl persistent, 128 VGPR).
// Chunk = 32 codes x 256 d (eh+el, 32 KB) double-buffered; 1 barrier/iter.
// Per chunk/wave: 32 ds_read_b128, 96 MFMA (3:1). Per-wave running min; collect
// codes with sc < rm + TAU into cand[row][CAP] via atomics (rare).
__global__ __launch_bounds__(256, 2) void coarse3_kernel(
    const float* __restrict__ z, const u16* __restrict__ ehp,
    const u16* __restrict__ elp, const float* __restrict__ esq,
    u32* __restrict__ cand, u32* __restrict__ cnt) {
  __shared__ char smem[65536];   // 2 bufs x [eh 16KB | el 16KB]
  const int t = threadIdx.x;
  const int w = t >> 6, l = t & 63;
  const int l16 = l & 15, lq = l >> 4;
  const int rowbase = blockIdx.x * 128 + w * 32;

  // persistent z fragments (B operand): row = rowbase + rs*16 + l16, k = s*32+lq*8+j
  short8 bzh[2][8], bzl[2][8];
  #pragma unroll
  for (int rs = 0; rs < 2; ++rs) {
    const float* zp = z + (size_t)(rowbase + rs*16 + l16) * D_DIM + lq*8;
    #pragma unroll
    for (int s = 0; s < 8; ++s) {
      float4 f0 = *(const float4*)(zp + s*32);
      float4 f1 = *(const float4*)(zp + s*32 + 4);
      float f[8] = {f0.x,f0.y,f0.z,f0.w,f1.x,f1.y,f1.z,f1.w};
      short8 h, lo;
      #pragma unroll
      for (int j = 0; j < 8; ++j) {
        u16 hb = f2bf(f[j]);
        h[j]  = (short)hb;
        lo[j] = (short)f2bf(f[j] - bf2f(hb));
      }
      bzh[rs][s] = h; bzl[rs][s] = lo;
    }
  }

  uint4 stg[8];
  // prologue: stage chunk 0 into buf 0
  #pragma unroll
  for (int q = 0; q < 4; ++q) {
    stg[q]   = *(const uint4*)((const char*)ehp + q*4096 + t*16);
    stg[4+q] = *(const uint4*)((const char*)elp + q*4096 + t*16);
  }
  #pragma unroll
  for (int q = 0; q < 4; ++q) {
    *(uint4*)(smem + q*4096 + t*16)         = stg[q];
    *(uint4*)(smem + 16384 + q*4096 + t*16) = stg[4+q];
  }
  __syncthreads();

  float rm[2] = {FLT_MAX, FLT_MAX};

  for (int cc = 0; cc < 128; ++cc) {
    const int cur = cc & 1;
    // T14: issue next-chunk loads early (hidden under MFMA phase)
    if (cc + 1 < 128) {
      #pragma unroll
      for (int q = 0; q < 4; ++q) {
        stg[q]   = *(const uint4*)((const char*)ehp + (size_t)(cc+1)*16384 + q*4096 + t*16);
        stg[4+q] = *(const uint4*)((const char*)elp + (size_t)(cc+1)*16384 + q*4096 + t*16);
      }
    }
    // esq for this chunk: sub0 codes lq*4..+3, sub1 at +16
    float4 e0 = *(const float4*)(esq + cc*32 + lq*4);
    float4 e1 = *(const float4*)(esq + cc*32 + 16 + lq*4);

    f32x4 acc[2][2] = {};   // [sub][rs], fully unrolled indexing only
    const char* bb = smem + cur*32768;
    #pragma unroll
    for (int s = 0; s < 8; ++s) {
      const int ao = s*1024 + lq*256 + l16*16;
      short8 ah0 = *(const short8*)(bb + ao);
      short8 ah1 = *(const short8*)(bb + 8192 + ao);
      short8 al0 = *(const short8*)(bb + 16384 + ao);
      short8 al1 = *(const short8*)(bb + 24576 + ao);
      #pragma unroll
      for (int rs = 0; rs < 2; ++rs) {
        acc[0][rs] = __builtin_amdgcn_mfma_f32_16x16x32_bf16(ah0, bzh[rs][s], acc[0][rs], 0,0,0);
        acc[0][rs] = __builtin_amdgcn_mfma_f32_16x16x32_bf16(ah0, bzl[rs][s], acc[0][rs], 0,0,0);
        acc[0][rs] = __builtin_amdgcn_mfma_f32_16x16x32_bf16(al0, bzh[rs][s], acc[0][rs], 0,0,0);
        acc[1][rs] = __builtin_amdgcn_mfma_f32_16x16x32_bf16(ah1, bzh[rs][s], acc[1][rs], 0,0,0);
        acc[1][rs] = __builtin_amdgcn_mfma_f32_16x16x32_bf16(ah1, bzl[rs][s], acc[1][rs], 0,0,0);
        acc[1][rs] = __builtin_amdgcn_mfma_f32_16x16x32_bf16(al1, bzh[rs][s], acc[1][rs], 0,0,0);
      }
    }

    // pass 1: chunk-min per rowset (in-lane over sub,r; cross-lane over lq groups)
    #pragma unroll
    for (int rs = 0; rs < 2; ++rs) {
      float m = FLT_MAX;
      #pragma unroll
      for (int r = 0; r < 4; ++r) {
        m = fminf(m, fmaf(-2.0f, acc[0][rs][r], ((const float*)&e0)[r]));
        m = fminf(m, fmaf(-2.0f, acc[1][rs][r], ((const float*)&e1)[r]));
      }
      m = fminf(m, __shfl_xor(m, 16));
      m = fminf(m, __shfl_xor(m, 32));
      rm[rs] = fminf(rm[rs], m);
    }
    // pass 2: collect (rare)
    bool hit = false;
    #pragma unroll
    for (int rs = 0; rs < 2; ++rs)
      #pragma unroll
      for (int r = 0; r < 4; ++r) {
        hit |= fmaf(-2.0f, acc[0][rs][r], ((const float*)&e0)[r]) < rm[rs] + TAU;
        hit |= fmaf(-2.0f, acc[1][rs][r], ((const float*)&e1)[r]) < rm[rs] + TAU;
      }
    if (hit) {
      #pragma unroll
      for (int sub = 0; sub < 2; ++sub)
        #pragma unroll
        for (int rs = 0; rs < 2; ++rs)
          #pragma unroll
          for (int r = 0; r < 4; ++r) {
            float ev = (sub == 0) ? ((const float*)&e0)[r] : ((const float*)&e1)[r];
            float sc = fmaf(-2.0f, acc[sub][rs][r], ev);
            if (sc < rm[rs] + TAU) {
              int row  = rowbase + rs*16 + l16;
              int code = cc*32 + sub*16 + lq*4 + r;
              u32 pos = atomicAdd(&cnt[row], 1u);
              if (pos < CAP) cand[(size_t)row*CAP + pos] = (u32)code;
            }
          }
    }
    // write-late: staged chunk cc+1 into the other buffer
    if (cc + 1 < 128) {
      char* wb = smem + (cur^1)*32768;
      #pragma unroll
      for (int q = 0; q < 4; ++q) {
        *(uint4*)(wb + q*4096 + t*16)         = stg[q];
        *(uint4*)(wb + 16384 + q*4096 + t*16) = stg[4+q];
      }
    }
    __syncthreads();
  }
}

// ---------- resolve: np-exact scoring of shortlist, (score, code) lexicographic min ----------
__global__ __launch_bounds__(256) void resolve_kernel(
    const float* __restrict__ z, const float* __restrict__ cb,
    const float* __restrict__ esq, const u32* __restrict__ cand,
    const u32* __restrict__ cnt, int* __restrict__ idx,
    int* __restrict__ flag, u32* __restrict__ counter) {
  __shared__ float zs[16][256];
  __shared__ float sco[16][16];
  __shared__ int   scd[16][16];
  const int t = threadIdx.x;
  const int r = t >> 4, s = t & 15;
  const int row0 = blockIdx.x * 16;
  #pragma unroll
  for (int q = 0; q < 4; ++q) {
    int g = t + 256*q;
    ((float4*)&zs[0][0])[g] = ((const float4*)(z + (size_t)row0 * D_DIM))[g];
  }
  __syncthreads();
  const int row = row0 + r;
  const u32 n = cnt[row];
  const int m = (n < CAP) ? (int)n : CAP;
  float myscore = FLT_MAX; int mycode = 0x7FFFFFFF;
  if (s < m) {
    int code = (int)cand[(size_t)row*CAP + s];
    float zsq = np_sumsq256(&zs[r][0]);
    const float4* e4 = (const float4*)(cb + (size_t)code * D_DIM);
    float acc = 0.0f;
    for (int dq = 0; dq < 64; ++dq) {
      float4 ev = e4[dq];
      float4 zv = *(const float4*)&zs[r][dq*4];
      acc = __fmaf_rn(zv.x, ev.x, acc);
      acc = __fmaf_rn(zv.y, ev.y, acc);
      acc = __fmaf_rn(zv.z, ev.z, acc);
      acc = __fmaf_rn(zv.w, ev.w, acc);
    }
    myscore = np_score(zsq, esq[code], acc);
    mycode = code;
  }
  sco[r][s] = myscore; scd[r][s] = mycode;
  __syncthreads();
  if (s == 0) {
    if (n > CAP) {
      idx[row] = 0;
      u32 p = atomicAdd(counter, 1u);
      flag[p] = row;
    } else {
      float bs = sco[r][0]; int bc = scd[r][0];
      for (int i = 1; i < m; ++i) {
        float os = sco[r][i]; int oc = scd[r][i];
        if (os < bs || (os == bs && oc < bc)) { bs = os; bc = oc; }
      }
      idx[row] = bc;
    }
  }
}

// ---------- full np-exact rescan for overflow rows (expected ~none) ----------
__global__ __launch_bounds__(256) void refine_np_kernel(
    const float* __restrict__ z, const float* __restrict__ cb,
    const float* __restrict__ esq, int* __restrict__ idx_out,
    const int* __restrict__ flag, const u32* __restrict__ counter) {
  __shared__ float zrow[RR][D_DIM];
  __shared__ float zsq[RR];
  __shared__ float rbest[256];
  __shared__ int   rbidx[256];
  const int t = threadIdx.x;
  const u32 cntv = *counter;
  const u32 ngroups = (cntv + RR - 1) / RR;
  for (u32 g = blockIdx.x; g < ngroups; g += gridDim.x) {
    __syncthreads();
    const int nr = (int)min((u32)RR, cntv - g*RR);
    #pragma unroll
    for (int r = 0; r < RR; ++r) {
      int fi = (int)(g*RR) + ((r < nr) ? r : 0);
      int row = flag[fi];
      zrow[r][t] = z[(size_t)row * D_DIM + t];
    }
    __syncthreads();
    if (t < RR) zsq[t] = np_sumsq256(&zrow[t][0]);
    __syncthreads();
    float best[RR]; int bidx[RR];
    #pragma unroll
    for (int r = 0; r < RR; ++r) { best[r] = FLT_MAX; bidx[r] = 0x7fffffff; }
    for (int mblk = 0; mblk < K_CB / 256; ++mblk) {
      const int k = mblk*256 + t;
      const float4* e4 = (const float4*)(cb + (size_t)k * D_DIM);
      float acc[RR];
      #pragma unroll
      for (int r = 0; r < RR; ++r) acc[r] = 0.0f;
      for (int dq = 0; dq < D_DIM/4; ++dq) {
        float4 ev = e4[dq];
        #pragma unroll
        for (int r = 0; r < RR; ++r) {
          acc[r] = __fmaf_rn(zrow[r][dq*4+0], ev.x, acc[r]);
          acc[r] = __fmaf_rn(zrow[r][dq*4+1], ev.y, acc[r]);
          acc[r] = __fmaf_rn(zrow[r][dq*4+2], ev.z, acc[r]);
          acc[r] = __fmaf_rn(zrow[r][dq*4+3], ev.w, acc[r]);
        }
      }
      const float ek = esq[k];
      #pragma unroll
      for (int r = 0; r < RR; ++r) {
        float sc = np_score(zsq[r], ek, acc[r]);
        if (sc < best[r]) { best[r] = sc; bidx[r] = k; }
      }
    }
    for (int r = 0; r < RR; ++r) {
      __syncthreads();
      rbest[t] = best[r]; rbidx[t] = bidx[r];
      __syncthreads();
      for (int off = 128; off > 0; off >>= 1) {
        if (t < off) {
          float ob = rbest[t+off]; int oi = rbidx[t+off];
          if (ob < rbest[t] || (ob == rbest[t] && oi < rbidx[t])) {
            rbest[t] = ob; rbidx[t] = oi;
          }
        }
        __syncthreads();
      }
      if (t == 0 && r < nr) idx_out[flag[g*RR + r]] = rbidx[0];
    }
  }
}

// ---------- gather + outputs + loss ----------
__global__ __launch_bounds__(256) void output_kernel(
    const float4* __restrict__ z4, const float4* __restrict__ cb4,
    const int* __restrict__ idx_out, float* __restrict__ out,
    double* __restrict__ partials) {
  const int g  = blockIdx.x * 256 + threadIdx.x;
  const int n  = g >> 6;
  const int dq = g & 63;
  const int id = idx_out[n];
  float4 q  = cb4[(size_t)id * (D_DIM/4) + dq];
  float4 zv = z4[(size_t)n  * (D_DIM/4) + dq];
  float dx = q.x - zv.x, dy = q.y - zv.y, dz = q.z - zv.z, dw = q.w - zv.w;
  double psum = (double)dx*dx + (double)dy*dy + (double)dz*dz + (double)dw*dw;
  size_t base = 1 + (size_t)n * D_DIM + (size_t)dq * 4;
  out[base+0] = q.x; out[base+1] = q.y; out[base+2] = q.z; out[base+3] = q.w;
  if (dq == 0) out[1 + (size_t)N_ROWS*D_DIM + n] = (float)id;
  __shared__ double sred[256];
  sred[threadIdx.x] = psum;
  __syncthreads();
  for (int off = 128; off > 0; off >>= 1) {
    if (threadIdx.x < off) sred[threadIdx.x] += sred[threadIdx.x + off];
    __syncthreads();
  }
  if (threadIdx.x == 0) partials[blockIdx.x] = sred[0];
}

__global__ __launch_bounds__(256) void loss_kernel(const double* __restrict__ partials,
                                                   float* __restrict__ out) {
  const int t = threadIdx.x;
  double s = 0.0;
  for (int m = 0; m < NUM_OUT_BLOCKS/256; ++m) s += partials[t + 256*m];
  __shared__ double sred[256];
  sred[t] = s;
  __syncthreads();
  for (int off = 128; off > 0; off >>= 1) {
    if (t < off) sred[t] += sred[t + off];
    __syncthreads();
  }
  if (t == 0) out[0] = (float)(1.25 * sred[0] / ((double)N_ROWS * (double)D_DIM));
}

extern "C" void kernel_launch(void* const* d_in, const int* in_sizes, int n_in,
                              void* d_out, int out_size, void* d_ws, size_t ws_size,
                              hipStream_t stream) {
  const float* z  = (const float*)d_in[0];
  const float* cb = (const float*)d_in[1];
  float* out = (float*)d_out;
  char*  ws  = (char*)d_ws;
  char*  ob  = (char*)d_out;

  u16* ehp  = (u16*)(ob + SC_EHP);
  u16* elp  = (u16*)(ob + SC_ELP);
  u32* cand = (u32*)(ob + SC_CAND);
  u32* cnt  = (u32*)(ob + SC_CNT);

  u32*    counter  = (u32*)   (ws + WS_COUNTER);
  float*  esq      = (float*) (ws + WS_ESQ);
  int*    idx      = (int*)   (ws + WS_IDX);
  int*    flag     = (int*)   (ws + WS_FLAG);
  double* partials = (double*)(ws + WS_PART);

  (void)hipMemsetAsync(ws, 0, 16, stream);
  (void)hipMemsetAsync(cnt, 0, N_ROWS*4, stream);

  esq_np_kernel<<<K_CB/256, 256, 0, stream>>>(cb, esq);
  esplit3_kernel<<<(K_CB*32)/256, 256, 0, stream>>>(cb, ehp, elp);
  coarse3_kernel<<<N_ROWS/128, 256, 0, stream>>>(z, ehp, elp, esq, cand, cnt);
  resolve_kernel<<<N_ROWS/16, 256, 0, stream>>>(z, cb, esq, cand, cnt, idx, flag, counter);
  refine_np_kernel<<<256, 256, 0, stream>>>(z, cb, esq, idx, flag, counter);
  output_kernel<<<NUM_OUT_BLOCKS, 256, 0, stream>>>((const float4*)z, (const float4*)cb,
                                                    idx, out, partials);
  loss_kernel<<<1, 256, 0, stream>>>(partials, out);
}

// Round 9
// 695.658 us; speedup vs baseline: 1.5076x; 1.5076x over previous
//
#include <hip/hip_runtime.h>
#include <float.h>

typedef __attribute__((ext_vector_type(8))) short short8;
typedef __attribute__((ext_vector_type(16))) float f32x16;
typedef unsigned short u16;

#define N_ROWS 65536
#define K_CB   4096
#define D_DIM  256
#define TAU    1.0e-3f
#define RR     8

// old-path tile params (fallback)
#define RB 128
#define KB 128
#define DB 32

// workspace layout (bytes)
#define WS_COUNTER 0
#define WS_ESQ     16
#define WS_IDX     (WS_ESQ + K_CB*4)
#define WS_FLAG    (WS_IDX + N_ROWS*4)
#define WS_PART    (WS_FLAG + N_ROWS*4)
#define NUM_OUT_BLOCKS ((N_ROWS*(D_DIM/4))/256)   // 16384
#define WS_EH      (WS_PART + NUM_OUT_BLOCKS*8)
#define WS_EL      (WS_EH + K_CB*D_DIM*2)
#define WS_NEEDED  (WS_EL + (size_t)K_CB*D_DIM*2)

// ---------- bf16 split helpers (RNE) ----------
__device__ __forceinline__ u16 f2bf(float x) {
  unsigned int u = __float_as_uint(x);
  unsigned int r = (u + 0x7fffu + ((u >> 16) & 1u)) >> 16;
  return (u16)r;
}
__device__ __forceinline__ float bf2f(u16 b) {
  return __uint_as_float((unsigned int)b << 16);
}
// np-exact final combine: fl( fl(zsq+esq) - fl(2*dot) )
__device__ __forceinline__ float np_score(float zsq, float ek, float dot) {
#pragma clang fp contract(off)
  float t1 = zsq + ek;
  float t2 = 2.0f * dot;
  return t1 - t2;
}

// ---------- numpy-emulated pairwise sum of squares ----------
__device__ __forceinline__ float np_sum128_sq(const float* p) {
#pragma clang fp contract(off)
  float r0 = p[0]*p[0], r1 = p[1]*p[1], r2 = p[2]*p[2], r3 = p[3]*p[3];
  float r4 = p[4]*p[4], r5 = p[5]*p[5], r6 = p[6]*p[6], r7 = p[7]*p[7];
  for (int i = 8; i < 128; i += 8) {
    r0 += p[i+0]*p[i+0]; r1 += p[i+1]*p[i+1];
    r2 += p[i+2]*p[i+2]; r3 += p[i+3]*p[i+3];
    r4 += p[i+4]*p[i+4]; r5 += p[i+5]*p[i+5];
    r6 += p[i+6]*p[i+6]; r7 += p[i+7]*p[i+7];
  }
  return ((r0+r1)+(r2+r3))+((r4+r5)+(r6+r7));
}
__device__ __forceinline__ float np_sumsq256(const float* p) {
#pragma clang fp contract(off)
  float a = np_sum128_sq(p);
  float b = np_sum128_sq(p + 128);
  return a + b;
}

__global__ __launch_bounds__(256) void esq_np_kernel(const float* __restrict__ cb,
                                                     float* __restrict__ esq) {
  const int k = blockIdx.x * 256 + threadIdx.x;
  esq[k] = np_sumsq256(cb + (size_t)k * D_DIM);
}

// ---------- codebook split into MFMA-fragment-permuted bf16 hi/lo ----------
// Chunk kc = 32 codes. Element layout within chunk (8192 elems = 16 KB):
//   off = d8*256 + c*8 + j   (d8 = d>>3, c = code&31, j = d&7)
// B-frag ds_read for k-step s, lane l: contiguous 16B at
//   s*1024 + (l>>5)*512 + (l&31)*16  bytes — conflict-free. [R4-proven]
__global__ __launch_bounds__(256) void esplit_perm_kernel(const float* __restrict__ cb,
                                                          u16* __restrict__ ehp,
                                                          u16* __restrict__ elp) {
  const int g  = blockIdx.x * 256 + threadIdx.x;   // K*D/8 threads
  const int k  = g >> 5;
  const int d8 = g & 31;
  const int kc = k >> 5, c = k & 31;
  const float* src = cb + (size_t)k * D_DIM + d8 * 8;
  float4 f0 = *(const float4*)src;
  float4 f1 = *(const float4*)(src + 4);
  float f[8] = {f0.x, f0.y, f0.z, f0.w, f1.x, f1.y, f1.z, f1.w};
  short8 h, lo;
  #pragma unroll
  for (int j = 0; j < 8; ++j) {
    u16 hb = f2bf(f[j]);
    h[j]  = (short)hb;
    lo[j] = (short)f2bf(f[j] - bf2f(hb));
  }
  const size_t off = (size_t)kc * 8192 + (size_t)d8 * 256 + (size_t)c * 8;
  *(short8*)(ehp + off) = h;
  *(short8*)(elp + off) = lo;
}

// ---------------- 32x32x16 split-bf16 MFMA argmin (R4 structure) ----------------
// 256 thr = 4 waves; wave owns 32 rows (A hi/lo persistent in 128 VGPRs).
// B chunks (32 codes x 256 d, hi+lo = 32 KB) double-buffered in LDS.
// R9 change vs R4: 3 independent accumulator chains (hh, lh, hl) to break the
// MFMA dependency chain (R4: 48 chained MFMAs -> 53% MfmaUtil); staging split
// into two 4-reg halves straddling the MFMA halves to hold VGPR demand ~250.
__global__ __launch_bounds__(256, 2) void mfma_argmin32_kernel(
    const float* __restrict__ z, const u16* __restrict__ ehp,
    const u16* __restrict__ elp, const float* __restrict__ esq,
    int* __restrict__ idx_out, int* __restrict__ flag,
    unsigned int* __restrict__ counter) {
  __shared__ u16 smem[2 * 16384];   // 64 KB
  const int t   = threadIdx.x;
  const int w   = t >> 6;
  const int l   = t & 63;
  const int col = l & 31;
  const int hi  = l >> 5;
  const int row = blockIdx.x * 128 + w * 32 + col;

  // A fragments: z row split to bf16 hi/lo, 16 k-steps of 16
  short8 ah[16], al[16];
  {
    const float* zr = z + (size_t)row * D_DIM + hi * 8;
    #pragma unroll
    for (int s = 0; s < 16; ++s) {
      float4 f0 = *(const float4*)(zr + s * 16);
      float4 f1 = *(const float4*)(zr + s * 16 + 4);
      float f[8] = {f0.x, f0.y, f0.z, f0.w, f1.x, f1.y, f1.z, f1.w};
      short8 h, lo;
      #pragma unroll
      for (int j = 0; j < 8; ++j) {
        u16 hb = f2bf(f[j]);
        h[j]  = (short)hb;
        lo[j] = (short)f2bf(f[j] - bf2f(hb));
      }
      ah[s] = h; al[s] = lo;
    }
  }

  float m1[16], m2[16]; int ic[16];
  #pragma unroll
  for (int r = 0; r < 16; ++r) { m1[r] = FLT_MAX; m2[r] = FLT_MAX; ic[r] = 0; }

  uint4 stg[4];
  // prologue: stage chunk 0 into buf 0 (eh half, then el half)
  {
    #pragma unroll
    for (int q = 0; q < 4; ++q)
      stg[q] = *(const uint4*)((const char*)ehp + q * 4096 + t * 16);
    #pragma unroll
    for (int q = 0; q < 4; ++q)
      *(uint4*)((char*)smem + q * 4096 + t * 16) = stg[q];
    #pragma unroll
    for (int q = 0; q < 4; ++q)
      stg[q] = *(const uint4*)((const char*)elp + q * 4096 + t * 16);
    #pragma unroll
    for (int q = 0; q < 4; ++q)
      *(uint4*)((char*)smem + 16384 + q * 4096 + t * 16) = stg[q];
  }
  __syncthreads();

  const int boff = hi * 512 + col * 16;
  for (int kc = 0; kc < 128; ++kc) {
    const int cur = kc & 1;
    const char* bb = (const char*)smem + cur * 32768;
    char* wb = (char*)smem + (cur ^ 1) * 32768;
    const bool hn = (kc + 1 < 128);

    // T14: issue next-chunk eh loads early
    if (hn) {
      #pragma unroll
      for (int q = 0; q < 4; ++q)
        stg[q] = *(const uint4*)((const char*)ehp + (size_t)(kc + 1) * 16384 + q * 4096 + t * 16);
    }

    f32x16 ahh = {}, alh = {}, ahl = {};   // 3 independent chains
    #pragma unroll
    for (int s = 0; s < 8; ++s) {
      short8 bh = *(const short8*)(bb + s * 1024 + boff);
      short8 bl = *(const short8*)(bb + 16384 + s * 1024 + boff);
      ahh = __builtin_amdgcn_mfma_f32_32x32x16_bf16(ah[s], bh, ahh, 0, 0, 0);
      alh = __builtin_amdgcn_mfma_f32_32x32x16_bf16(al[s], bh, alh, 0, 0, 0);
      ahl = __builtin_amdgcn_mfma_f32_32x32x16_bf16(ah[s], bl, ahl, 0, 0, 0);
    }

    // write eh half; issue el loads
    if (hn) {
      #pragma unroll
      for (int q = 0; q < 4; ++q)
        *(uint4*)(wb + q * 4096 + t * 16) = stg[q];
      #pragma unroll
      for (int q = 0; q < 4; ++q)
        stg[q] = *(const uint4*)((const char*)elp + (size_t)(kc + 1) * 16384 + q * 4096 + t * 16);
    }

    #pragma unroll
    for (int s = 8; s < 16; ++s) {
      short8 bh = *(const short8*)(bb + s * 1024 + boff);
      short8 bl = *(const short8*)(bb + 16384 + s * 1024 + boff);
      ahh = __builtin_amdgcn_mfma_f32_32x32x16_bf16(ah[s], bh, ahh, 0, 0, 0);
      alh = __builtin_amdgcn_mfma_f32_32x32x16_bf16(al[s], bh, alh, 0, 0, 0);
      ahl = __builtin_amdgcn_mfma_f32_32x32x16_bf16(ah[s], bl, ahl, 0, 0, 0);
    }

    // branchless top-2 (kc ascending -> first-index tie-break within lane)
    const float ev = esq[kc * 32 + col];
    #pragma unroll
    for (int r = 0; r < 16; ++r) {
      float sum = (ahh[r] + alh[r]) + ahl[r];
      float sc = fmaf(-2.0f, sum, ev);
      bool lt = sc < m1[r];
      ic[r] = lt ? kc : ic[r];
      m2[r] = fminf(m2[r], fmaxf(m1[r], sc));
      m1[r] = fminf(m1[r], sc);
    }

    // write el half into the other buffer
    if (hn) {
      #pragma unroll
      for (int q = 0; q < 4; ++q)
        *(uint4*)(wb + 16384 + q * 4096 + t * 16) = stg[q];
    }
    __syncthreads();
  }

  // merge top-2 across the 32 lanes of this half (codes of each chunk)
  #pragma unroll
  for (int r = 0; r < 16; ++r) {
    float a1 = m1[r], a2 = m2[r];
    int cd = ic[r] * 32 + col;
    #pragma unroll
    for (int off = 1; off < 32; off <<= 1) {
      float b1 = __shfl_xor(a1, off);
      float b2 = __shfl_xor(a2, off);
      int   bc = __shfl_xor(cd, off);
      bool take = (b1 < a1) || (b1 == a1 && bc < cd);
      float nm2 = take ? fminf(a1, b2) : fminf(a2, b1);
      if (take) { a1 = b1; cd = bc; }
      a2 = nm2;
    }
    if (col == 0) {
      const int orow = blockIdx.x * 128 + w * 32 + (r & 3) + 8 * (r >> 2) + 4 * hi;
      idx_out[orow] = cd;
      if (a2 - a1 < TAU) {
        unsigned int p = atomicAdd(counter, 1u);
        flag[p] = orow;
      }
    }
  }
}

// ---------------- fallback fp32 argmin (if ws too small) ----------------
__global__ __launch_bounds__(256, 2) void argmin_kernel(
    const float4* __restrict__ z4, const float4* __restrict__ cb4,
    const float* __restrict__ esq, int* __restrict__ idx_out,
    int* __restrict__ flag, unsigned int* __restrict__ counter) {
  __shared__ float zt[DB][RB];
  __shared__ float et[DB][KB];
  const int t  = threadIdx.x;
  const int tr = t >> 4;
  const int tc = t & 15;
  const int row0 = blockIdx.x * RB;

  float min1[8], min2[8]; int idx1[8];
  #pragma unroll
  for (int i = 0; i < 8; ++i) { min1[i] = FLT_MAX; min2[i] = FLT_MAX; idx1[i] = 0; }

  for (int kc = 0; kc < K_CB / KB; ++kc) {
    const int k0 = kc * KB;
    float acc[8][8];
    #pragma unroll
    for (int i = 0; i < 8; ++i)
      #pragma unroll
      for (int j = 0; j < 8; ++j) acc[i][j] = 0.0f;

    float esqv[8];
    #pragma unroll
    for (int j = 0; j < 8; ++j) esqv[j] = esq[k0 + tc*8 + j];

    for (int dt = 0; dt < D_DIM / DB; ++dt) {
      __syncthreads();
      #pragma unroll
      for (int m = 0; m < 4; ++m) {
        int u  = t + 256*m;
        int dq = u & 7;
        int r  = u >> 3;
        float4 v = z4[(size_t)(row0 + r)*(D_DIM/4) + dt*8 + dq];
        zt[dq*4+0][r] = v.x; zt[dq*4+1][r] = v.y; zt[dq*4+2][r] = v.z; zt[dq*4+3][r] = v.w;
        float4 wv = cb4[(size_t)(k0 + r)*(D_DIM/4) + dt*8 + dq];
        et[dq*4+0][r] = wv.x; et[dq*4+1][r] = wv.y; et[dq*4+2][r] = wv.z; et[dq*4+3][r] = wv.w;
      }
      __syncthreads();

      #pragma unroll 8
      for (int d = 0; d < DB; ++d) {
        float4 za = *(const float4*)&zt[d][tr*8];
        float4 zb = *(const float4*)&zt[d][tr*8+4];
        float4 ea = *(const float4*)&et[d][tc*8];
        float4 eb = *(const float4*)&et[d][tc*8+4];
        float zr[8] = {za.x, za.y, za.z, za.w, zb.x, zb.y, zb.z, zb.w};
        float ev[8] = {ea.x, ea.y, ea.z, ea.w, eb.x, eb.y, eb.z, eb.w};
        #pragma unroll
        for (int i = 0; i < 8; ++i)
          #pragma unroll
          for (int j = 0; j < 8; ++j)
            acc[i][j] += zr[i] * ev[j];
      }
    }

    #pragma unroll
    for (int j = 0; j < 8; ++j) {
      const int k = k0 + tc*8 + j;
      #pragma unroll
      for (int i = 0; i < 8; ++i) {
        float s = esqv[j] - 2.0f * acc[i][j];
        if (s < min1[i]) { min2[i] = min1[i]; min1[i] = s; idx1[i] = k; }
        else if (s < min2[i]) { min2[i] = s; }
      }
    }
  }

  #pragma unroll
  for (int i = 0; i < 8; ++i) {
    float m1 = min1[i], m2 = min2[i]; int id = idx1[i];
    #pragma unroll
    for (int off = 1; off < 16; off <<= 1) {
      float om1 = __shfl_xor(m1, off);
      float om2 = __shfl_xor(m2, off);
      int   oid = __shfl_xor(id, off);
      bool take = (om1 < m1) || (om1 == m1 && oid < id);
      float nm2 = take ? fminf(m1, om2) : fminf(m2, om1);
      if (take) { m1 = om1; id = oid; }
      m2 = nm2;
    }
    if (tc == 0) {
      int row = row0 + tr*8 + i;
      idx_out[row] = id;
      if (m2 - m1 < TAU) {
        unsigned int p = atomicAdd(counter, 1u);
        flag[p] = row;
      }
    }
  }
}

// ---------------- numpy-fp32-emulated re-score of ambiguous rows ----------------
__global__ __launch_bounds__(256) void refine_np_kernel(
    const float* __restrict__ z, const float* __restrict__ cb,
    const float* __restrict__ esq, int* __restrict__ idx_out,
    const int* __restrict__ flag, const unsigned int* __restrict__ counter) {
  __shared__ float zrow[RR][D_DIM];
  __shared__ float zsq[RR];
  __shared__ float rbest[256];
  __shared__ int   rbidx[256];
  const int t = threadIdx.x;
  const unsigned int cnt = *counter;
  const unsigned int ngroups = (cnt + RR - 1) / RR;

  for (unsigned int g = blockIdx.x; g < ngroups; g += gridDim.x) {
    __syncthreads();
    const int nr = (int)min((unsigned int)RR, cnt - g*RR);
    #pragma unroll
    for (int r = 0; r < RR; ++r) {
      int fi = (int)(g*RR) + ((r < nr) ? r : 0);
      int row = flag[fi];
      zrow[r][t] = z[(size_t)row * D_DIM + t];
    }
    __syncthreads();
    if (t < RR) zsq[t] = np_sumsq256(&zrow[t][0]);
    __syncthreads();

    float best[RR]; int bidx[RR];
    #pragma unroll
    for (int r = 0; r < RR; ++r) { best[r] = FLT_MAX; bidx[r] = 0x7fffffff; }

    for (int m = 0; m < K_CB / 256; ++m) {
      const int k = m*256 + t;
      const float4* e4 = (const float4*)(cb + (size_t)k * D_DIM);
      float acc[RR];
      #pragma unroll
      for (int r = 0; r < RR; ++r) acc[r] = 0.0f;
      for (int dq = 0; dq < D_DIM/4; ++dq) {
        float4 ev = e4[dq];
        #pragma unroll
        for (int r = 0; r < RR; ++r) {
          acc[r] = __fmaf_rn(zrow[r][dq*4+0], ev.x, acc[r]);
          acc[r] = __fmaf_rn(zrow[r][dq*4+1], ev.y, acc[r]);
          acc[r] = __fmaf_rn(zrow[r][dq*4+2], ev.z, acc[r]);
          acc[r] = __fmaf_rn(zrow[r][dq*4+3], ev.w, acc[r]);
        }
      }
      const float ek = esq[k];
      #pragma unroll
      for (int r = 0; r < RR; ++r) {
        float sc = np_score(zsq[r], ek, acc[r]);
        if (sc < best[r]) { best[r] = sc; bidx[r] = k; }
      }
    }

    for (int r = 0; r < RR; ++r) {
      __syncthreads();
      rbest[t] = best[r]; rbidx[t] = bidx[r];
      __syncthreads();
      for (int off = 128; off > 0; off >>= 1) {
        if (t < off) {
          float ob = rbest[t+off]; int oi = rbidx[t+off];
          if (ob < rbest[t] || (ob == rbest[t] && oi < rbidx[t])) {
            rbest[t] = ob; rbidx[t] = oi;
          }
        }
        __syncthreads();
      }
      if (t == 0 && r < nr) idx_out[flag[g*RR + r]] = rbidx[0];
    }
  }
}

// ---------------- gather + outputs + loss partials ----------------
__global__ __launch_bounds__(256) void output_kernel(
    const float4* __restrict__ z4, const float4* __restrict__ cb4,
    const int* __restrict__ idx_out, float* __restrict__ out,
    double* __restrict__ partials) {
  const int g  = blockIdx.x * 256 + threadIdx.x;
  const int n  = g >> 6;
  const int dq = g & 63;
  const int id = idx_out[n];
  float4 q  = cb4[(size_t)id * (D_DIM/4) + dq];
  float4 zv = z4[(size_t)n  * (D_DIM/4) + dq];
  float dx = q.x - zv.x, dy = q.y - zv.y, dz = q.z - zv.z, dw = q.w - zv.w;
  double psum = (double)dx*dx + (double)dy*dy + (double)dz*dz + (double)dw*dw;
  size_t base = 1 + (size_t)n * D_DIM + (size_t)dq * 4;
  out[base+0] = q.x; out[base+1] = q.y; out[base+2] = q.z; out[base+3] = q.w;
  if (dq == 0) out[1 + (size_t)N_ROWS*D_DIM + n] = (float)id;

  __shared__ double sred[256];
  sred[threadIdx.x] = psum;
  __syncthreads();
  for (int off = 128; off > 0; off >>= 1) {
    if (threadIdx.x < off) sred[threadIdx.x] += sred[threadIdx.x + off];
    __syncthreads();
  }
  if (threadIdx.x == 0) partials[blockIdx.x] = sred[0];
}

__global__ __launch_bounds__(256) void loss_kernel(const double* __restrict__ partials,
                                                   float* __restrict__ out) {
  const int t = threadIdx.x;
  double s = 0.0;
  for (int m = 0; m < NUM_OUT_BLOCKS/256; ++m) s += partials[t + 256*m];
  __shared__ double sred[256];
  sred[t] = s;
  __syncthreads();
  for (int off = 128; off > 0; off >>= 1) {
    if (t < off) sred[t] += sred[t + off];
    __syncthreads();
  }
  if (t == 0) out[0] = (float)(1.25 * sred[0] / ((double)N_ROWS * (double)D_DIM));
}

extern "C" void kernel_launch(void* const* d_in, const int* in_sizes, int n_in,
                              void* d_out, int out_size, void* d_ws, size_t ws_size,
                              hipStream_t stream) {
  const float* z  = (const float*)d_in[0];
  const float* cb = (const float*)d_in[1];
  float* out = (float*)d_out;
  char* ws = (char*)d_ws;

  unsigned int* counter = (unsigned int*)(ws + WS_COUNTER);
  float*  esq      = (float*) (ws + WS_ESQ);
  int*    idx      = (int*)   (ws + WS_IDX);
  int*    flag     = (int*)   (ws + WS_FLAG);
  double* partials = (double*)(ws + WS_PART);

  (void)hipMemsetAsync(ws, 0, 16, stream);
  esq_np_kernel<<<K_CB/256, 256, 0, stream>>>(cb, esq);

  if (ws_size >= WS_NEEDED) {
    u16* ehp = (u16*)(ws + WS_EH);
    u16* elp = (u16*)(ws + WS_EL);
    esplit_perm_kernel<<<(K_CB*(D_DIM/8))/256, 256, 0, stream>>>(cb, ehp, elp);
    mfma_argmin32_kernel<<<N_ROWS/128, 256, 0, stream>>>(z, ehp, elp, esq,
                                                         idx, flag, counter);
  } else {
    argmin_kernel<<<N_ROWS/RB, 256, 0, stream>>>((const float4*)z, (const float4*)cb,
                                                 esq, idx, flag, counter);
  }

  refine_np_kernel<<<256, 256, 0, stream>>>(z, cb, esq, idx, flag, counter);
  output_kernel<<<NUM_OUT_BLOCKS, 256, 0, stream>>>((const float4*)z, (const float4*)cb,
                                                    idx, out, partials);
  loss_kernel<<<1, 256, 0, stream>>>(partials, out);
}

// Round 10
// 599.737 us; speedup vs baseline: 1.7487x; 1.1599x over previous
//
#include <hip/hip_runtime.h>
#include <float.h>

typedef __attribute__((ext_vector_type(8))) short short8;
typedef __attribute__((ext_vector_type(16))) float f32x16;
typedef unsigned short u16;

#define N_ROWS 65536
#define K_CB   4096
#define D_DIM  256
#define TAU    1.0e-3f
#define RR     8

// old-path tile params (fallback)
#define RB 128
#define KB 128
#define DB 32

// workspace layout (bytes)
#define WS_COUNTER 0
#define WS_ESQ     16
#define WS_IDX     (WS_ESQ + K_CB*4)
#define WS_FLAG    (WS_IDX + N_ROWS*4)
#define WS_PART    (WS_FLAG + N_ROWS*4)
#define NUM_OUT_BLOCKS ((N_ROWS*(D_DIM/4))/256)   // 16384
#define WS_EH      (WS_PART + NUM_OUT_BLOCKS*8)
#define WS_EL      (WS_EH + K_CB*D_DIM*2)
#define WS_NEEDED  (WS_EL + (size_t)K_CB*D_DIM*2)

// ---------- bf16 split helpers (RNE) ----------
__device__ __forceinline__ u16 f2bf(float x) {
  unsigned int u = __float_as_uint(x);
  unsigned int r = (u + 0x7fffu + ((u >> 16) & 1u)) >> 16;
  return (u16)r;
}
__device__ __forceinline__ float bf2f(u16 b) {
  return __uint_as_float((unsigned int)b << 16);
}
// np-exact final combine: fl( fl(zsq+esq) - fl(2*dot) )
__device__ __forceinline__ float np_score(float zsq, float ek, float dot) {
#pragma clang fp contract(off)
  float t1 = zsq + ek;
  float t2 = 2.0f * dot;
  return t1 - t2;
}

// ---------- numpy-emulated pairwise sum of squares ----------
__device__ __forceinline__ float np_sum128_sq(const float* p) {
#pragma clang fp contract(off)
  float r0 = p[0]*p[0], r1 = p[1]*p[1], r2 = p[2]*p[2], r3 = p[3]*p[3];
  float r4 = p[4]*p[4], r5 = p[5]*p[5], r6 = p[6]*p[6], r7 = p[7]*p[7];
  for (int i = 8; i < 128; i += 8) {
    r0 += p[i+0]*p[i+0]; r1 += p[i+1]*p[i+1];
    r2 += p[i+2]*p[i+2]; r3 += p[i+3]*p[i+3];
    r4 += p[i+4]*p[i+4]; r5 += p[i+5]*p[i+5];
    r6 += p[i+6]*p[i+6]; r7 += p[i+7]*p[i+7];
  }
  return ((r0+r1)+(r2+r3))+((r4+r5)+(r6+r7));
}
__device__ __forceinline__ float np_sumsq256(const float* p) {
#pragma clang fp contract(off)
  float a = np_sum128_sq(p);
  float b = np_sum128_sq(p + 128);
  return a + b;
}

__global__ __launch_bounds__(256) void esq_np_kernel(const float* __restrict__ cb,
                                                     float* __restrict__ esq) {
  const int k = blockIdx.x * 256 + threadIdx.x;
  esq[k] = np_sumsq256(cb + (size_t)k * D_DIM);
}

// ---------- codebook split into MFMA-fragment-permuted bf16 hi/lo ----------
// Chunk kc = 32 codes. Element layout within chunk (8192 elems = 16 KB):
//   off = d8*256 + c*8 + j   (d8 = d>>3, c = code&31, j = d&7)
// B-frag ds_read for k-step s, lane l: contiguous 16B at
//   s*1024 + (l>>5)*512 + (l&31)*16  bytes — conflict-free. [R4-proven]
__global__ __launch_bounds__(256) void esplit_perm_kernel(const float* __restrict__ cb,
                                                          u16* __restrict__ ehp,
                                                          u16* __restrict__ elp) {
  const int g  = blockIdx.x * 256 + threadIdx.x;   // K*D/8 threads
  const int k  = g >> 5;
  const int d8 = g & 31;
  const int kc = k >> 5, c = k & 31;
  const float* src = cb + (size_t)k * D_DIM + d8 * 8;
  float4 f0 = *(const float4*)src;
  float4 f1 = *(const float4*)(src + 4);
  float f[8] = {f0.x, f0.y, f0.z, f0.w, f1.x, f1.y, f1.z, f1.w};
  short8 h, lo;
  #pragma unroll
  for (int j = 0; j < 8; ++j) {
    u16 hb = f2bf(f[j]);
    h[j]  = (short)hb;
    lo[j] = (short)f2bf(f[j] - bf2f(hb));
  }
  const size_t off = (size_t)kc * 8192 + (size_t)d8 * 256 + (size_t)c * 8;
  *(short8*)(ehp + off) = h;
  *(short8*)(elp + off) = lo;
}

// ---------------- 32x32x16 split-bf16 MFMA argmin (R4 schedule) ----------------
// 256 thr = 4 waves; wave owns 32 rows (A hi/lo persistent in 128 VGPRs).
// B chunks (32 codes x 256 d, hi+lo = 32 KB) double-buffered in LDS via
// global_load_lds width-16 (no staging VGPRs, no ds_writes). 48 MFMAs per
// chunk spread round-robin over 4 independent accumulator chains (same-chain
// issue gap 4 >= dep latency/throughput ratio) — breaks R4's 40-cyc dep stall.
__global__ __launch_bounds__(256, 2) void mfma_argmin32_kernel(
    const float* __restrict__ z, const u16* __restrict__ ehp,
    const u16* __restrict__ elp, const float* __restrict__ esq,
    int* __restrict__ idx_out, int* __restrict__ flag,
    unsigned int* __restrict__ counter) {
  __shared__ u16 smem[2 * 16384];   // 64 KB
  const int t   = threadIdx.x;
  const int w   = t >> 6;
  const int l   = t & 63;
  const int col = l & 31;
  const int hi  = l >> 5;
  const int row = blockIdx.x * 128 + w * 32 + col;
  const int wbase = w * 1024;       // wave-uniform LDS byte base within quarter

  // A fragments: z row split to bf16 hi/lo, 16 k-steps of 16
  short8 ah[16], al[16];
  {
    const float* zr = z + (size_t)row * D_DIM + hi * 8;
    #pragma unroll
    for (int s = 0; s < 16; ++s) {
      float4 f0 = *(const float4*)(zr + s * 16);
      float4 f1 = *(const float4*)(zr + s * 16 + 4);
      float f[8] = {f0.x, f0.y, f0.z, f0.w, f1.x, f1.y, f1.z, f1.w};
      short8 h, lo;
      #pragma unroll
      for (int j = 0; j < 8; ++j) {
        u16 hb = f2bf(f[j]);
        h[j]  = (short)hb;
        lo[j] = (short)f2bf(f[j] - bf2f(hb));
      }
      ah[s] = h; al[s] = lo;
    }
  }

  float m1[16], m2[16]; int ic[16];
  #pragma unroll
  for (int r = 0; r < 16; ++r) { m1[r] = FLT_MAX; m2[r] = FLT_MAX; ic[r] = 0; }

  // async global->LDS staging of one chunk (eh 16KB + el 16KB)
  #define STAGE(KCN, BUF) do {                                                  \
    char* lb = (char*)smem + (BUF) * 32768;                                     \
    const char* gh = (const char*)ehp + (size_t)(KCN) * 16384;                  \
    const char* gl = (const char*)elp + (size_t)(KCN) * 16384;                  \
    _Pragma("unroll")                                                           \
    for (int q = 0; q < 4; ++q) {                                               \
      __builtin_amdgcn_global_load_lds(                                         \
        (const __attribute__((address_space(1))) void*)(gh + q*4096 + t*16),    \
        (__attribute__((address_space(3))) void*)(lb + q*4096 + wbase),         \
        16, 0, 0);                                                              \
      __builtin_amdgcn_global_load_lds(                                         \
        (const __attribute__((address_space(1))) void*)(gl + q*4096 + t*16),    \
        (__attribute__((address_space(3))) void*)(lb + 16384 + q*4096 + wbase), \
        16, 0, 0);                                                              \
    }                                                                           \
  } while (0)

  STAGE(0, 0);
  __syncthreads();

  const int boff = hi * 512 + col * 16;
  for (int kc = 0; kc < 128; ++kc) {
    const int cur = kc & 1;
    if (kc + 1 < 128) STAGE(kc + 1, cur ^ 1);   // issue early; drained at barrier
    const char* bb = (const char*)smem + cur * 32768;

    f32x16 c0 = {}, c1 = {}, c2 = {}, c3 = {};
    // round-robin chain rotation, period 4: same-chain gap = 4 MFMAs
    #define MFMA3(S, A0, A1, A2) do {                                           \
      short8 bh = *(const short8*)(bb + (S) * 1024 + boff);                     \
      short8 bl = *(const short8*)(bb + 16384 + (S) * 1024 + boff);             \
      A0 = __builtin_amdgcn_mfma_f32_32x32x16_bf16(ah[S], bh, A0, 0, 0, 0);     \
      A1 = __builtin_amdgcn_mfma_f32_32x32x16_bf16(al[S], bh, A1, 0, 0, 0);     \
      A2 = __builtin_amdgcn_mfma_f32_32x32x16_bf16(ah[S], bl, A2, 0, 0, 0);     \
    } while (0)
    MFMA3(0,  c0, c1, c2);  MFMA3(1,  c3, c0, c1);
    MFMA3(2,  c2, c3, c0);  MFMA3(3,  c1, c2, c3);
    MFMA3(4,  c0, c1, c2);  MFMA3(5,  c3, c0, c1);
    MFMA3(6,  c2, c3, c0);  MFMA3(7,  c1, c2, c3);
    MFMA3(8,  c0, c1, c2);  MFMA3(9,  c3, c0, c1);
    MFMA3(10, c2, c3, c0);  MFMA3(11, c1, c2, c3);
    MFMA3(12, c0, c1, c2);  MFMA3(13, c3, c0, c1);
    MFMA3(14, c2, c3, c0);  MFMA3(15, c1, c2, c3);
    #undef MFMA3

    // branchless top-2 (kc ascending -> first-index tie-break within lane)
    const float ev = esq[kc * 32 + col];
    #pragma unroll
    for (int r = 0; r < 16; ++r) {
      float sum = (c0[r] + c1[r]) + (c2[r] + c3[r]);
      float sc = fmaf(-2.0f, sum, ev);
      bool lt = sc < m1[r];
      ic[r] = lt ? kc : ic[r];
      m2[r] = fminf(m2[r], fmaxf(m1[r], sc));
      m1[r] = fminf(m1[r], sc);
    }
    __syncthreads();   // drains vmcnt: next chunk's LDS writes landed
  }
  #undef STAGE

  // merge top-2 across the 32 lanes of this half (codes of each chunk)
  #pragma unroll
  for (int r = 0; r < 16; ++r) {
    float a1 = m1[r], a2 = m2[r];
    int cd = ic[r] * 32 + col;
    #pragma unroll
    for (int off = 1; off < 32; off <<= 1) {
      float b1 = __shfl_xor(a1, off);
      float b2 = __shfl_xor(a2, off);
      int   bc = __shfl_xor(cd, off);
      bool take = (b1 < a1) || (b1 == a1 && bc < cd);
      float nm2 = take ? fminf(a1, b2) : fminf(a2, b1);
      if (take) { a1 = b1; cd = bc; }
      a2 = nm2;
    }
    if (col == 0) {
      const int orow = blockIdx.x * 128 + w * 32 + (r & 3) + 8 * (r >> 2) + 4 * hi;
      idx_out[orow] = cd;
      if (a2 - a1 < TAU) {
        unsigned int p = atomicAdd(counter, 1u);
        flag[p] = orow;
      }
    }
  }
}

// ---------------- fallback fp32 argmin (if ws too small) ----------------
__global__ __launch_bounds__(256, 2) void argmin_kernel(
    const float4* __restrict__ z4, const float4* __restrict__ cb4,
    const float* __restrict__ esq, int* __restrict__ idx_out,
    int* __restrict__ flag, unsigned int* __restrict__ counter) {
  __shared__ float zt[DB][RB];
  __shared__ float et[DB][KB];
  const int t  = threadIdx.x;
  const int tr = t >> 4;
  const int tc = t & 15;
  const int row0 = blockIdx.x * RB;

  float min1[8], min2[8]; int idx1[8];
  #pragma unroll
  for (int i = 0; i < 8; ++i) { min1[i] = FLT_MAX; min2[i] = FLT_MAX; idx1[i] = 0; }

  for (int kc = 0; kc < K_CB / KB; ++kc) {
    const int k0 = kc * KB;
    float acc[8][8];
    #pragma unroll
    for (int i = 0; i < 8; ++i)
      #pragma unroll
      for (int j = 0; j < 8; ++j) acc[i][j] = 0.0f;

    float esqv[8];
    #pragma unroll
    for (int j = 0; j < 8; ++j) esqv[j] = esq[k0 + tc*8 + j];

    for (int dt = 0; dt < D_DIM / DB; ++dt) {
      __syncthreads();
      #pragma unroll
      for (int m = 0; m < 4; ++m) {
        int u  = t + 256*m;
        int dq = u & 7;
        int r  = u >> 3;
        float4 v = z4[(size_t)(row0 + r)*(D_DIM/4) + dt*8 + dq];
        zt[dq*4+0][r] = v.x; zt[dq*4+1][r] = v.y; zt[dq*4+2][r] = v.z; zt[dq*4+3][r] = v.w;
        float4 wv = cb4[(size_t)(k0 + r)*(D_DIM/4) + dt*8 + dq];
        et[dq*4+0][r] = wv.x; et[dq*4+1][r] = wv.y; et[dq*4+2][r] = wv.z; et[dq*4+3][r] = wv.w;
      }
      __syncthreads();

      #pragma unroll 8
      for (int d = 0; d < DB; ++d) {
        float4 za = *(const float4*)&zt[d][tr*8];
        float4 zb = *(const float4*)&zt[d][tr*8+4];
        float4 ea = *(const float4*)&et[d][tc*8];
        float4 eb = *(const float4*)&et[d][tc*8+4];
        float zr[8] = {za.x, za.y, za.z, za.w, zb.x, zb.y, zb.z, zb.w};
        float ev[8] = {ea.x, ea.y, ea.z, ea.w, eb.x, eb.y, eb.z, eb.w};
        #pragma unroll
        for (int i = 0; i < 8; ++i)
          #pragma unroll
          for (int j = 0; j < 8; ++j)
            acc[i][j] += zr[i] * ev[j];
      }
    }

    #pragma unroll
    for (int j = 0; j < 8; ++j) {
      const int k = k0 + tc*8 + j;
      #pragma unroll
      for (int i = 0; i < 8; ++i) {
        float s = esqv[j] - 2.0f * acc[i][j];
        if (s < min1[i]) { min2[i] = min1[i]; min1[i] = s; idx1[i] = k; }
        else if (s < min2[i]) { min2[i] = s; }
      }
    }
  }

  #pragma unroll
  for (int i = 0; i < 8; ++i) {
    float m1 = min1[i], m2 = min2[i]; int id = idx1[i];
    #pragma unroll
    for (int off = 1; off < 16; off <<= 1) {
      float om1 = __shfl_xor(m1, off);
      float om2 = __shfl_xor(m2, off);
      int   oid = __shfl_xor(id, off);
      bool take = (om1 < m1) || (om1 == m1 && oid < id);
      float nm2 = take ? fminf(m1, om2) : fminf(m2, om1);
      if (take) { m1 = om1; id = oid; }
      m2 = nm2;
    }
    if (tc == 0) {
      int row = row0 + tr*8 + i;
      idx_out[row] = id;
      if (m2 - m1 < TAU) {
        unsigned int p = atomicAdd(counter, 1u);
        flag[p] = row;
      }
    }
  }
}

// ---------------- numpy-fp32-emulated re-score of ambiguous rows ----------------
__global__ __launch_bounds__(256) void refine_np_kernel(
    const float* __restrict__ z, const float* __restrict__ cb,
    const float* __restrict__ esq, int* __restrict__ idx_out,
    const int* __restrict__ flag, const unsigned int* __restrict__ counter) {
  __shared__ float zrow[RR][D_DIM];
  __shared__ float zsq[RR];
  __shared__ float rbest[256];
  __shared__ int   rbidx[256];
  const int t = threadIdx.x;
  const unsigned int cnt = *counter;
  const unsigned int ngroups = (cnt + RR - 1) / RR;

  for (unsigned int g = blockIdx.x; g < ngroups; g += gridDim.x) {
    __syncthreads();
    const int nr = (int)min((unsigned int)RR, cnt - g*RR);
    #pragma unroll
    for (int r = 0; r < RR; ++r) {
      int fi = (int)(g*RR) + ((r < nr) ? r : 0);
      int row = flag[fi];
      zrow[r][t] = z[(size_t)row * D_DIM + t];
    }
    __syncthreads();
    if (t < RR) zsq[t] = np_sumsq256(&zrow[t][0]);
    __syncthreads();

    float best[RR]; int bidx[RR];
    #pragma unroll
    for (int r = 0; r < RR; ++r) { best[r] = FLT_MAX; bidx[r] = 0x7fffffff; }

    for (int m = 0; m < K_CB / 256; ++m) {
      const int k = m*256 + t;
      const float4* e4 = (const float4*)(cb + (size_t)k * D_DIM);
      float acc[RR];
      #pragma unroll
      for (int r = 0; r < RR; ++r) acc[r] = 0.0f;
      for (int dq = 0; dq < D_DIM/4; ++dq) {
        float4 ev = e4[dq];
        #pragma unroll
        for (int r = 0; r < RR; ++r) {
          acc[r] = __fmaf_rn(zrow[r][dq*4+0], ev.x, acc[r]);
          acc[r] = __fmaf_rn(zrow[r][dq*4+1], ev.y, acc[r]);
          acc[r] = __fmaf_rn(zrow[r][dq*4+2], ev.z, acc[r]);
          acc[r] = __fmaf_rn(zrow[r][dq*4+3], ev.w, acc[r]);
        }
      }
      const float ek = esq[k];
      #pragma unroll
      for (int r = 0; r < RR; ++r) {
        float sc = np_score(zsq[r], ek, acc[r]);
        if (sc < best[r]) { best[r] = sc; bidx[r] = k; }
      }
    }

    for (int r = 0; r < RR; ++r) {
      __syncthreads();
      rbest[t] = best[r]; rbidx[t] = bidx[r];
      __syncthreads();
      for (int off = 128; off > 0; off >>= 1) {
        if (t < off) {
          float ob = rbest[t+off]; int oi = rbidx[t+off];
          if (ob < rbest[t] || (ob == rbest[t] && oi < rbidx[t])) {
            rbest[t] = ob; rbidx[t] = oi;
          }
        }
        __syncthreads();
      }
      if (t == 0 && r < nr) idx_out[flag[g*RR + r]] = rbidx[0];
    }
  }
}

// ---------------- gather + outputs + loss partials ----------------
__global__ __launch_bounds__(256) void output_kernel(
    const float4* __restrict__ z4, const float4* __restrict__ cb4,
    const int* __restrict__ idx_out, float* __restrict__ out,
    double* __restrict__ partials) {
  const int g  = blockIdx.x * 256 + threadIdx.x;
  const int n  = g >> 6;
  const int dq = g & 63;
  const int id = idx_out[n];
  float4 q  = cb4[(size_t)id * (D_DIM/4) + dq];
  float4 zv = z4[(size_t)n  * (D_DIM/4) + dq];
  float dx = q.x - zv.x, dy = q.y - zv.y, dz = q.z - zv.z, dw = q.w - zv.w;
  double psum = (double)dx*dx + (double)dy*dy + (double)dz*dz + (double)dw*dw;
  size_t base = 1 + (size_t)n * D_DIM + (size_t)dq * 4;
  out[base+0] = q.x; out[base+1] = q.y; out[base+2] = q.z; out[base+3] = q.w;
  if (dq == 0) out[1 + (size_t)N_ROWS*D_DIM + n] = (float)id;

  __shared__ double sred[256];
  sred[threadIdx.x] = psum;
  __syncthreads();
  for (int off = 128; off > 0; off >>= 1) {
    if (threadIdx.x < off) sred[threadIdx.x] += sred[threadIdx.x + off];
    __syncthreads();
  }
  if (threadIdx.x == 0) partials[blockIdx.x] = sred[0];
}

__global__ __launch_bounds__(256) void loss_kernel(const double* __restrict__ partials,
                                                   float* __restrict__ out) {
  const int t = threadIdx.x;
  double s = 0.0;
  for (int m = 0; m < NUM_OUT_BLOCKS/256; ++m) s += partials[t + 256*m];
  __shared__ double sred[256];
  sred[t] = s;
  __syncthreads();
  for (int off = 128; off > 0; off >>= 1) {
    if (t < off) sred[t] += sred[t + off];
    __syncthreads();
  }
  if (t == 0) out[0] = (float)(1.25 * sred[0] / ((double)N_ROWS * (double)D_DIM));
}

extern "C" void kernel_launch(void* const* d_in, const int* in_sizes, int n_in,
                              void* d_out, int out_size, void* d_ws, size_t ws_size,
                              hipStream_t stream) {
  const float* z  = (const float*)d_in[0];
  const float* cb = (const float*)d_in[1];
  float* out = (float*)d_out;
  char* ws = (char*)d_ws;

  unsigned int* counter = (unsigned int*)(ws + WS_COUNTER);
  float*  esq      = (float*) (ws + WS_ESQ);
  int*    idx      = (int*)   (ws + WS_IDX);
  int*    flag     = (int*)   (ws + WS_FLAG);
  double* partials = (double*)(ws + WS_PART);

  (void)hipMemsetAsync(ws, 0, 16, stream);
  esq_np_kernel<<<K_CB/256, 256, 0, stream>>>(cb, esq);

  if (ws_size >= WS_NEEDED) {
    u16* ehp = (u16*)(ws + WS_EH);
    u16* elp = (u16*)(ws + WS_EL);
    esplit_perm_kernel<<<(K_CB*(D_DIM/8))/256, 256, 0, stream>>>(cb, ehp, elp);
    mfma_argmin32_kernel<<<N_ROWS/128, 256, 0, stream>>>(z, ehp, elp, esq,
                                                         idx, flag, counter);
  } else {
    argmin_kernel<<<N_ROWS/RB, 256, 0, stream>>>((const float4*)z, (const float4*)cb,
                                                 esq, idx, flag, counter);
  }

  refine_np_kernel<<<256, 256, 0, stream>>>(z, cb, esq, idx, flag, counter);
  output_kernel<<<NUM_OUT_BLOCKS, 256, 0, stream>>>((const float4*)z, (const float4*)cb,
                                                    idx, out, partials);
  loss_kernel<<<1, 256, 0, stream>>>(partials, out);
}